// Round 6
// baseline (314.502 us; speedup 1.0000x reference)
//
#include <hip/hip_runtime.h>
#include <stdint.h>
#include <math.h>

#define SEQ 4096
#define DM  1024
#define NH  16
#define DH  64
#define PPAD 72
#define LOG2E 1.44269504088896341f

typedef short bf16x8 __attribute__((ext_vector_type(8)));
typedef short bf16x4 __attribute__((ext_vector_type(4)));
typedef float f32x4  __attribute__((ext_vector_type(4)));

typedef const __attribute__((address_space(1))) short* gptr_t;
typedef __attribute__((address_space(3))) short* lptr_t;

__device__ __forceinline__ short f2bf(float f) {
    union { float f; uint32_t u; } x; x.f = f;
    uint32_t r = (x.u + 0x7fffu + ((x.u >> 16) & 1u)) >> 16;
    return (short)r;
}
__device__ __forceinline__ short f2bf_trunc(float f) {
    union { float f; uint32_t u; } x; x.f = f;
    return (short)(x.u >> 16);
}

__device__ __forceinline__ void load_lds16(const short* g, const short* l) {
    __builtin_amdgcn_global_load_lds((gptr_t)(uintptr_t)g,
                                     (lptr_t)(uint32_t)(uintptr_t)l, 16, 0, 0);
}

// ---- fused prep: blocks [0,2048) convert x fp32->bf16; blocks [2048,2816)
//      transpose w [1024][3072] -> wtb [3072][1024] bf16, Q cols pre-scaled ----
__global__ __launch_bounds__(256) void cvt_fused(const float* __restrict__ x,
                                                 const float* __restrict__ w,
                                                 short* __restrict__ xb,
                                                 short* __restrict__ wtb) {
    __shared__ float T[64][69];
    const int b = blockIdx.x;
    if (b < 2048) {
        const int i = (b * 256 + threadIdx.x) * 8;
        float4 a0 = ((const float4*)(x + i))[0];
        float4 a1 = ((const float4*)(x + i))[1];
        bf16x8 p;
        p[0]=f2bf(a0.x); p[1]=f2bf(a0.y); p[2]=f2bf(a0.z); p[3]=f2bf(a0.w);
        p[4]=f2bf(a1.x); p[5]=f2bf(a1.y); p[6]=f2bf(a1.z); p[7]=f2bf(a1.w);
        *(bf16x8*)(xb + i) = p;
        return;
    }
    const int bb = b - 2048;
    const int n0 = (bb % 48) * 64, k0 = (bb / 48) * 64;
    const int t = threadIdx.x;
    {
        const int kr = t >> 4, nc = (t & 15) * 4;
        #pragma unroll
        for (int i = 0; i < 4; ++i) {
            float4 v = *(const float4*)(w + (size_t)(k0 + kr + i * 16) * 3072 + n0 + nc);
            T[kr + i * 16][nc + 0] = v.x; T[kr + i * 16][nc + 1] = v.y;
            T[kr + i * 16][nc + 2] = v.z; T[kr + i * 16][nc + 3] = v.w;
        }
    }
    __syncthreads();
    const int nr = t >> 4, kc = (t & 15) * 4;
    #pragma unroll
    for (int i = 0; i < 4; ++i) {
        const int n = n0 + nr + i * 16;
        const float sc = (n >= 1024 && n < 2048) ? (LOG2E / 32.0f) : 1.0f;
        short4 o;
        o.x = f2bf(T[kc + 0][nr + i * 16] * sc);
        o.y = f2bf(T[kc + 1][nr + i * 16] * sc);
        o.z = f2bf(T[kc + 2][nr + i * 16] * sc);
        o.w = f2bf(T[kc + 3][nr + i * 16] * sc);
        *(short4*)(wtb + (size_t)n * 1024 + k0 + kc) = o;
    }
}

// ---- QKV GEMM (m97 structure): 128x128 tile, BK=64, global_load_lds ----
__global__ __launch_bounds__(256) void qkv_gemm(const short* __restrict__ xb,
                                                const short* __restrict__ wtb,
                                                short* __restrict__ kq,
                                                short* __restrict__ vt) {
    __shared__ short As[128 * 64];
    __shared__ short Bs[128 * 64];
    const int col0 = blockIdx.y * 128, row0 = blockIdx.x * 128;
    const int tid = threadIdx.x, w = tid >> 6, lane = tid & 63;
    const int lmod = lane & 15, ldiv = lane >> 4;
    const int wr = (w >> 1) * 64, wc = (w & 1) * 64;

    f32x4 acc[4][4] = {};
    const short* Ag = xb  + (size_t)row0 * DM;
    const short* Bg = wtb + (size_t)col0 * DM;

    for (int k0 = 0; k0 < DM; k0 += 64) {
        __syncthreads();
        #pragma unroll
        for (int t = 0; t < 4; ++t) {
            const int o = (w * 4 + t) * 1024 + lane * 16;
            const int r = o >> 7, cs = (o & 127) >> 1;
            load_lds16(Ag + (size_t)r * DM + k0 + cs, As + (w * 4 + t) * 512);
            load_lds16(Bg + (size_t)r * DM + k0 + cs, Bs + (w * 4 + t) * 512);
        }
        __syncthreads();
        #pragma unroll
        for (int ks = 0; ks < 2; ++ks) {
            bf16x8 af[4], bf[4];
            #pragma unroll
            for (int i = 0; i < 4; ++i)
                af[i] = *(const bf16x8*)(As + (wr + i * 16 + lmod) * 64 + ks * 32 + ldiv * 8);
            #pragma unroll
            for (int j = 0; j < 4; ++j)
                bf[j] = *(const bf16x8*)(Bs + (wc + j * 16 + lmod) * 64 + ks * 32 + ldiv * 8);
            #pragma unroll
            for (int i = 0; i < 4; ++i)
                #pragma unroll
                for (int j = 0; j < 4; ++j)
                    acc[i][j] = __builtin_amdgcn_mfma_f32_16x16x32_bf16(af[i], bf[j], acc[i][j], 0, 0, 0);
        }
    }

    if (col0 < 2048) {
        #pragma unroll
        for (int i = 0; i < 4; ++i)
            #pragma unroll
            for (int j = 0; j < 4; ++j)
                #pragma unroll
                for (int r = 0; r < 4; ++r)
                    kq[(size_t)(row0 + wr + i * 16 + ldiv * 4 + r) * 2048
                       + col0 + wc + j * 16 + lmod] = f2bf(acc[i][j][r]);
    } else {
        #pragma unroll
        for (int i = 0; i < 4; ++i) {
            const int ig = row0 + wr + i * 16 + ldiv * 4;
            #pragma unroll
            for (int j = 0; j < 4; ++j) {
                const int cg = col0 + wc + j * 16 + lmod - 2048;
                const int h = cg >> 6, d = cg & 63;
                bf16x4 p;
                p[0]=f2bf(acc[i][j][0]); p[1]=f2bf(acc[i][j][1]);
                p[2]=f2bf(acc[i][j][2]); p[3]=f2bf(acc[i][j][3]);
                *(bf16x4*)(vt + (size_t)(h * 64 + d) * SEQ + ig) = p;
            }
        }
    }
}

// ---- flash attention, split-K 2-way: block (qt,h,s) does k-tiles
//      [s*(qt+1), (s+1)*(qt+1)) -- both splits are exactly qt+1 tiles.
//      Writes UNNORMALIZED partial O (s=0 -> out buf, s=1 -> opart) + lsum.
//      Fixed-max exp2 softmax (Q pre-scaled by log2e/32), ALiBi in acc-init.
//      XOR-swizzled K/V LDS staging (no pad, conflict-free). 4 blocks/CU. ----
__global__ __launch_bounds__(256, 4) void attn(const short* __restrict__ kq,
                                               const short* __restrict__ vt,
                                               float* __restrict__ o0,
                                               float* __restrict__ o1,
                                               float* __restrict__ ls0,
                                               float* __restrict__ ls1) {
    __shared__ short Ks[64 * 64];
    __shared__ short Vs[64 * 64];
    __shared__ short Ps[4 * 32 * PPAD];

    // band-interleaved decode: per-CU resident set sums to 66 units
    const int b = blockIdx.x;
    const int band = b >> 8, pos = b & 255, g = pos >> 5;
    const int qt = (band & 1) ? (24 - band * 8 + g) : (31 - band * 8 - g);
    const int h = (pos >> 1) & 15, s = pos & 1;

    const int tid = threadIdx.x, w = tid >> 6, lane = tid & 63;
    const int lmod = lane & 15, ldiv = lane >> 4;
    const float slope2 = exp2f(-0.5f * (float)(h + 1)) * LOG2E;

    const int srow = tid >> 3;              // staging row 0..31
    const int sch  = tid & 7;               // staging logical chunk (8 shorts)
    const int swoff = srow * 64 + ((sch ^ (srow & 7)) << 3);   // swizzled
    const int xorm = lmod & 7;              // read-side swizzle
    const int cx0 = (0 * 4 + ldiv) ^ xorm;  // phys chunk, ks=0
    const int cx1 = (1 * 4 + ldiv) ^ xorm;  // phys chunk, ks=1
    const int rowbase = qt * 128 + w * 32;
    short* pw = Ps + w * 32 * PPAD;

    // Q fragments (2 m-blocks x 2 k-steps)
    bf16x8 qf[2][2];
    #pragma unroll
    for (int m = 0; m < 2; ++m) {
        const short* qp = kq + (size_t)(rowbase + m * 16 + lmod) * 2048 + 1024 + h * 64;
        qf[m][0] = *(const bf16x8*)(qp + ldiv * 8);
        qf[m][1] = *(const bf16x8*)(qp + 32 + ldiv * 8);
    }
    int db[2];
    float pre[2][4];
    #pragma unroll
    for (int m = 0; m < 2; ++m) {
        db[m] = lmod - (rowbase + m * 16 + ldiv * 4);
        #pragma unroll
        for (int r = 0; r < 4; ++r) pre[m][r] = slope2 * (float)(db[m] - r);
    }

    f32x4 O[2][4] = {};
    float lsum[2][4] = {};
    const int kt0 = s ? (qt + 1) : 0;
    const int kt1 = s ? (2 * qt + 2) : (qt + 1);

    uint4 ka0, ka1, va0, va1, kb0, kb1, vb0, vb1;

    auto sload = [&](int kt, uint4& k0, uint4& k1, uint4& v0, uint4& v1) {
        const short* kb_ = kq + (size_t)(kt * 64 + srow) * 2048 + h * 64 + sch * 8;
        k0 = *(const uint4*)kb_;
        k1 = *(const uint4*)(kb_ + (size_t)32 * 2048);
        const short* vb_ = vt + (size_t)(h * 64 + srow) * SEQ + kt * 64 + sch * 8;
        v0 = *(const uint4*)vb_;
        v1 = *(const uint4*)(vb_ + (size_t)32 * SEQ);
    };
    auto swrite = [&](const uint4& k0, const uint4& k1,
                      const uint4& v0, const uint4& v1) {
        *(uint4*)(Ks + swoff) = k0;
        *(uint4*)(Ks + swoff + 32 * 64) = k1;
        *(uint4*)(Vs + swoff) = v0;
        *(uint4*)(Vs + swoff + 32 * 64) = v1;
    };
    auto compute = [&](int kt, bool diag) {
        const float cb = slope2 * (float)(kt * 64);
        f32x4 sc[2][4];
        #pragma unroll
        for (int nt = 0; nt < 4; ++nt) {
            const float cn = cb + slope2 * (float)(nt * 16);
            #pragma unroll
            for (int m = 0; m < 2; ++m)
                #pragma unroll
                for (int r = 0; r < 4; ++r) sc[m][nt][r] = pre[m][r] + cn;
        }
        #pragma unroll
        for (int ks = 0; ks < 2; ++ks) {
            const int cxo = (ks ? cx1 : cx0) << 3;
            #pragma unroll
            for (int nt = 0; nt < 4; ++nt) {
                bf16x8 kf = *(const bf16x8*)(Ks + (nt * 16 + lmod) * 64 + cxo);
                #pragma unroll
                for (int m = 0; m < 2; ++m)
                    sc[m][nt] = __builtin_amdgcn_mfma_f32_16x16x32_bf16(qf[m][ks], kf, sc[m][nt], 0, 0, 0);
            }
        }
        const int dt = kt * 64;
        if (diag) {   // wave-uniform branch
            #pragma unroll
            for (int m = 0; m < 2; ++m)
                #pragma unroll
                for (int nt = 0; nt < 4; ++nt)
                    #pragma unroll
                    for (int r = 0; r < 4; ++r) {
                        float v = sc[m][nt][r];
                        if (dt + nt * 16 - r + db[m] > 0) v = -1e30f;
                        const float p = __builtin_amdgcn_exp2f(v);
                        lsum[m][r] += p;
                        pw[(m * 16 + ldiv * 4 + r) * PPAD + nt * 16 + lmod] = f2bf_trunc(p);
                    }
        } else {
            #pragma unroll
            for (int m = 0; m < 2; ++m)
                #pragma unroll
                for (int nt = 0; nt < 4; ++nt)
                    #pragma unroll
                    for (int r = 0; r < 4; ++r) {
                        const float p = __builtin_amdgcn_exp2f(sc[m][nt][r]);
                        lsum[m][r] += p;
                        pw[(m * 16 + ldiv * 4 + r) * PPAD + nt * 16 + lmod] = f2bf_trunc(p);
                    }
        }
        // P: same-wave LDS RAW (lgkmcnt ordering, no barrier)
        bf16x8 pa[2][2];
        #pragma unroll
        for (int m = 0; m < 2; ++m) {
            pa[m][0] = *(const bf16x8*)(pw + (m * 16 + lmod) * PPAD + ldiv * 8);
            pa[m][1] = *(const bf16x8*)(pw + (m * 16 + lmod) * PPAD + 32 + ldiv * 8);
        }
        #pragma unroll
        for (int ks = 0; ks < 2; ++ks) {
            const int cxo = (ks ? cx1 : cx0) << 3;
            #pragma unroll
            for (int nt = 0; nt < 4; ++nt) {
                bf16x8 vf = *(const bf16x8*)(Vs + (nt * 16 + lmod) * 64 + cxo);
                #pragma unroll
                for (int m = 0; m < 2; ++m)
                    O[m][nt] = __builtin_amdgcn_mfma_f32_16x16x32_bf16(pa[m][ks], vf, O[m][nt], 0, 0, 0);
            }
        }
    };

    sload(kt0, ka0, ka1, va0, va1);
    int kt = kt0;
    while (true) {
        if (kt + 1 < kt1) sload(kt + 1, kb0, kb1, vb0, vb1);
        __syncthreads();
        swrite(ka0, ka1, va0, va1);
        __syncthreads();
        compute(kt, kt >= 2 * qt);
        if (++kt >= kt1) break;
        if (kt + 1 < kt1) sload(kt + 1, ka0, ka1, va0, va1);
        __syncthreads();
        swrite(kb0, kb1, vb0, vb1);
        __syncthreads();
        compute(kt, kt >= 2 * qt);
        if (++kt >= kt1) break;
    }

    // reduce row sums across 16-lane groups
    #pragma unroll
    for (int m = 0; m < 2; ++m)
        #pragma unroll
        for (int r = 0; r < 4; ++r) {
            float v = lsum[m][r];
            v += __shfl_xor(v, 1, 16);
            v += __shfl_xor(v, 2, 16);
            v += __shfl_xor(v, 4, 16);
            v += __shfl_xor(v, 8, 16);
            lsum[m][r] = v;
        }

    float* ob = s ? o1 : o0;
    float* lb = s ? ls1 : ls0;
    #pragma unroll
    for (int m = 0; m < 2; ++m) {
        const int i0 = rowbase + m * 16 + ldiv * 4;
        #pragma unroll
        for (int nt = 0; nt < 4; ++nt)
            #pragma unroll
            for (int r = 0; r < 4; ++r)
                ob[(size_t)(i0 + r) * DM + h * 64 + nt * 16 + lmod] = O[m][nt][r];
    }
    if (lmod == 0) {
        #pragma unroll
        for (int m = 0; m < 2; ++m)
            #pragma unroll
            for (int r = 0; r < 4; ++r)
                lb[h * SEQ + rowbase + m * 16 + ldiv * 4 + r] = lsum[m][r];
    }
}

// ---- combine: out = (O0 + O1) / (l0 + l1) ----
__global__ __launch_bounds__(256) void combine(float* __restrict__ out,
                                               const float* __restrict__ opart,
                                               const float* __restrict__ ls0,
                                               const float* __restrict__ ls1) {
    const int i8 = (blockIdx.x * 256 + threadIdx.x) * 8;
    const int row = i8 >> 10, col = i8 & 1023, h = col >> 6;
    const float l = ls0[h * SEQ + row] + ls1[h * SEQ + row];
    const float rc = 1.0f / l;
    float4 a0 = *(const float4*)(out + i8);
    float4 a1 = *(const float4*)(out + i8 + 4);
    float4 b0 = *(const float4*)(opart + i8);
    float4 b1 = *(const float4*)(opart + i8 + 4);
    float4 c0, c1;
    c0.x = (a0.x + b0.x) * rc; c0.y = (a0.y + b0.y) * rc;
    c0.z = (a0.z + b0.z) * rc; c0.w = (a0.w + b0.w) * rc;
    c1.x = (a1.x + b1.x) * rc; c1.y = (a1.y + b1.y) * rc;
    c1.z = (a1.z + b1.z) * rc; c1.w = (a1.w + b1.w) * rc;
    *(float4*)(out + i8) = c0;
    *(float4*)(out + i8 + 4) = c1;
}

extern "C" void kernel_launch(void* const* d_in, const int* in_sizes, int n_in,
                              void* d_out, int out_size, void* d_ws, size_t ws_size,
                              hipStream_t stream) {
    const float* x = (const float*)d_in[0];   // [1,4096,1024] fp32
    const float* w = (const float*)d_in[1];   // [1024,3072] fp32
    float* out = (float*)d_out;

    char* ws = (char*)d_ws;
    short* kq    = (short*)(ws);                        // 16 MB: K|Q [4096][2048]
    short* vt    = (short*)(ws + ((size_t)16 << 20));   //  8 MB: V^T [16][64][4096]
    short* xb    = (short*)(ws + ((size_t)24 << 20));   //  8 MB: x bf16 (dead after gemm)
    short* wtb   = (short*)(ws + ((size_t)32 << 20));   //  6 MB: w^T bf16 (dead after gemm)
    float* opart = (float*)(ws + ((size_t)24 << 20));   // 16 MB: split-1 partial O (reuses xb/wtb)
    float* ls0   = (float*)(ws + ((size_t)40 << 20));   // 256 KB
    float* ls1   = (float*)(ws + ((size_t)40 << 20) + (256 << 10));

    cvt_fused<<<2048 + 768, 256, 0, stream>>>(x, w, xb, wtb);
    qkv_gemm <<<dim3(SEQ / 128, 3072 / 128), 256, 0, stream>>>(xb, wtb, kq, vt);
    attn     <<<1024, 256, 0, stream>>>(kq, vt, out, opart, ls0, ls1);
    combine  <<<SEQ * DM / (256 * 8), 256, 0, stream>>>(out, opart, ls0, ls1);
}

// Round 7
// 191.191 us; speedup vs baseline: 1.6450x; 1.6450x over previous
//
#include <hip/hip_runtime.h>
#include <stdint.h>
#include <math.h>

#define SEQ 4096
#define DM  1024
#define NH  16
#define DH  64
#define PPAD 72
#define LOG2E 1.44269504088896341f

typedef short bf16x8 __attribute__((ext_vector_type(8)));
typedef short bf16x4 __attribute__((ext_vector_type(4)));
typedef float f32x4  __attribute__((ext_vector_type(4)));

typedef const __attribute__((address_space(1))) short* gptr_t;
typedef __attribute__((address_space(3))) short* lptr_t;

__device__ __forceinline__ short f2bf(float f) {
    union { float f; uint32_t u; } x; x.f = f;
    uint32_t r = (x.u + 0x7fffu + ((x.u >> 16) & 1u)) >> 16;
    return (short)r;
}
__device__ __forceinline__ short f2bf_trunc(float f) {
    union { float f; uint32_t u; } x; x.f = f;
    return (short)(x.u >> 16);
}

__device__ __forceinline__ void load_lds16(const short* g, const short* l) {
    __builtin_amdgcn_global_load_lds((gptr_t)(uintptr_t)g,
                                     (lptr_t)(uint32_t)(uintptr_t)l, 16, 0, 0);
}

// ---- fused prep: blocks [0,2048) convert x fp32->bf16; blocks [2048,2816)
//      transpose w [1024][3072] -> wtb [3072][1024] bf16, Q cols pre-scaled ----
__global__ __launch_bounds__(256) void cvt_fused(const float* __restrict__ x,
                                                 const float* __restrict__ w,
                                                 short* __restrict__ xb,
                                                 short* __restrict__ wtb) {
    __shared__ float T[64][69];
    const int b = blockIdx.x;
    if (b < 2048) {
        const int i = (b * 256 + threadIdx.x) * 8;
        float4 a0 = ((const float4*)(x + i))[0];
        float4 a1 = ((const float4*)(x + i))[1];
        bf16x8 p;
        p[0]=f2bf(a0.x); p[1]=f2bf(a0.y); p[2]=f2bf(a0.z); p[3]=f2bf(a0.w);
        p[4]=f2bf(a1.x); p[5]=f2bf(a1.y); p[6]=f2bf(a1.z); p[7]=f2bf(a1.w);
        *(bf16x8*)(xb + i) = p;
        return;
    }
    const int bb = b - 2048;
    const int n0 = (bb % 48) * 64, k0 = (bb / 48) * 64;
    const int t = threadIdx.x;
    {
        const int kr = t >> 4, nc = (t & 15) * 4;
        #pragma unroll
        for (int i = 0; i < 4; ++i) {
            float4 v = *(const float4*)(w + (size_t)(k0 + kr + i * 16) * 3072 + n0 + nc);
            T[kr + i * 16][nc + 0] = v.x; T[kr + i * 16][nc + 1] = v.y;
            T[kr + i * 16][nc + 2] = v.z; T[kr + i * 16][nc + 3] = v.w;
        }
    }
    __syncthreads();
    const int nr = t >> 4, kc = (t & 15) * 4;
    #pragma unroll
    for (int i = 0; i < 4; ++i) {
        const int n = n0 + nr + i * 16;
        const float sc = (n >= 1024 && n < 2048) ? (LOG2E / 32.0f) : 1.0f;
        short4 o;
        o.x = f2bf(T[kc + 0][nr + i * 16] * sc);
        o.y = f2bf(T[kc + 1][nr + i * 16] * sc);
        o.z = f2bf(T[kc + 2][nr + i * 16] * sc);
        o.w = f2bf(T[kc + 3][nr + i * 16] * sc);
        *(short4*)(wtb + (size_t)n * 1024 + k0 + kc) = o;
    }
}

// ---- QKV GEMM (m97 structure): 128x128 tile, BK=64, global_load_lds ----
__global__ __launch_bounds__(256) void qkv_gemm(const short* __restrict__ xb,
                                                const short* __restrict__ wtb,
                                                short* __restrict__ kq,
                                                short* __restrict__ vt) {
    __shared__ short As[128 * 64];
    __shared__ short Bs[128 * 64];
    const int col0 = blockIdx.y * 128, row0 = blockIdx.x * 128;
    const int tid = threadIdx.x, w = tid >> 6, lane = tid & 63;
    const int lmod = lane & 15, ldiv = lane >> 4;
    const int wr = (w >> 1) * 64, wc = (w & 1) * 64;

    f32x4 acc[4][4] = {};
    const short* Ag = xb  + (size_t)row0 * DM;
    const short* Bg = wtb + (size_t)col0 * DM;

    for (int k0 = 0; k0 < DM; k0 += 64) {
        __syncthreads();
        #pragma unroll
        for (int t = 0; t < 4; ++t) {
            const int o = (w * 4 + t) * 1024 + lane * 16;
            const int r = o >> 7, cs = (o & 127) >> 1;
            load_lds16(Ag + (size_t)r * DM + k0 + cs, As + (w * 4 + t) * 512);
            load_lds16(Bg + (size_t)r * DM + k0 + cs, Bs + (w * 4 + t) * 512);
        }
        __syncthreads();
        #pragma unroll
        for (int ks = 0; ks < 2; ++ks) {
            bf16x8 af[4], bf[4];
            #pragma unroll
            for (int i = 0; i < 4; ++i)
                af[i] = *(const bf16x8*)(As + (wr + i * 16 + lmod) * 64 + ks * 32 + ldiv * 8);
            #pragma unroll
            for (int j = 0; j < 4; ++j)
                bf[j] = *(const bf16x8*)(Bs + (wc + j * 16 + lmod) * 64 + ks * 32 + ldiv * 8);
            #pragma unroll
            for (int i = 0; i < 4; ++i)
                #pragma unroll
                for (int j = 0; j < 4; ++j)
                    acc[i][j] = __builtin_amdgcn_mfma_f32_16x16x32_bf16(af[i], bf[j], acc[i][j], 0, 0, 0);
        }
    }

    if (col0 < 2048) {
        #pragma unroll
        for (int i = 0; i < 4; ++i)
            #pragma unroll
            for (int j = 0; j < 4; ++j)
                #pragma unroll
                for (int r = 0; r < 4; ++r)
                    kq[(size_t)(row0 + wr + i * 16 + ldiv * 4 + r) * 2048
                       + col0 + wc + j * 16 + lmod] = f2bf(acc[i][j][r]);
    } else {
        #pragma unroll
        for (int i = 0; i < 4; ++i) {
            const int ig = row0 + wr + i * 16 + ldiv * 4;
            #pragma unroll
            for (int j = 0; j < 4; ++j) {
                const int cg = col0 + wc + j * 16 + lmod - 2048;
                const int h = cg >> 6, d = cg & 63;
                bf16x4 p;
                p[0]=f2bf(acc[i][j][0]); p[1]=f2bf(acc[i][j][1]);
                p[2]=f2bf(acc[i][j][2]); p[3]=f2bf(acc[i][j][3]);
                *(bf16x4*)(vt + (size_t)(h * 64 + d) * SEQ + ig) = p;
            }
        }
    }
}

// ---- flash attention, split-K 2-way, global_load_lds staging (no prefetch
//      VGPRs), XOR swizzle applied on the GLOBAL source address, nt-outer
//      S-loop for low register pressure. 4 blocks/CU. ----
__global__ __launch_bounds__(256, 4) void attn(const short* __restrict__ kq,
                                               const short* __restrict__ vt,
                                               float* __restrict__ o0,
                                               float* __restrict__ o1,
                                               float* __restrict__ ls0,
                                               float* __restrict__ ls1) {
    __shared__ short Ks[64 * 64];
    __shared__ short Vs[64 * 64];
    __shared__ short Ps[4 * 32 * PPAD];

    // band-interleaved decode: per-CU resident set sums to 66 units
    const int b = blockIdx.x;
    const int band = b >> 8, pos = b & 255, g = pos >> 5;
    const int qt = (band & 1) ? (24 - band * 8 + g) : (31 - band * 8 - g);
    const int h = (pos >> 1) & 15, s = pos & 1;

    const int tid = threadIdx.x, w = tid >> 6, lane = tid & 63;
    const int lmod = lane & 15, ldiv = lane >> 4;
    const float slope2 = exp2f(-0.5f * (float)(h + 1)) * LOG2E;

    // staging: wave w stages rows w*16..w*16+15 of both K and V tiles.
    // lane l -> row w*16 + (l>>3) (+8 for 2nd load), phys chunk l&7;
    // global logical chunk = phys ^ (row&7)  (swizzle on source address).
    const int sr0 = w * 16 + (lane >> 3), sr1 = sr0 + 8;
    const int sc0 = (lane & 7) ^ (sr0 & 7), sc1 = (lane & 7) ^ (sr1 & 7);

    const int xorm = lmod & 7;              // read-side swizzle
    const int cx0 = ldiv ^ xorm;            // phys chunk, ks=0
    const int cx1 = (4 + ldiv) ^ xorm;      // phys chunk, ks=1
    const int rowbase = qt * 128 + w * 32;
    short* pw = Ps + w * 32 * PPAD;

    // Q fragments (2 m-blocks x 2 k-steps)
    bf16x8 qf[2][2];
    #pragma unroll
    for (int m = 0; m < 2; ++m) {
        const short* qp = kq + (size_t)(rowbase + m * 16 + lmod) * 2048 + 1024 + h * 64;
        qf[m][0] = *(const bf16x8*)(qp + ldiv * 8);
        qf[m][1] = *(const bf16x8*)(qp + 32 + ldiv * 8);
    }
    int db[2];
    float pre[2][4];
    #pragma unroll
    for (int m = 0; m < 2; ++m) {
        db[m] = lmod - (rowbase + m * 16 + ldiv * 4);
        #pragma unroll
        for (int r = 0; r < 4; ++r) pre[m][r] = slope2 * (float)(db[m] - r);
    }

    f32x4 O[2][4] = {};
    float lsum[2][4] = {};
    const int kt0 = s ? (qt + 1) : 0;
    const int kt1 = s ? (2 * qt + 2) : (qt + 1);

    for (int kt = kt0; kt < kt1; ++kt) {
        __syncthreads();   // prev compute done reading Ks/Vs
        {
            const short* kb = kq + (size_t)(kt * 64) * 2048 + h * 64;
            load_lds16(kb + (size_t)sr0 * 2048 + sc0 * 8, Ks + (w * 16) * 64);
            load_lds16(kb + (size_t)sr1 * 2048 + sc1 * 8, Ks + (w * 16 + 8) * 64);
            const short* vb = vt + (size_t)(h * 64) * SEQ + kt * 64;
            load_lds16(vb + (size_t)sr0 * SEQ + sc0 * 8, Vs + (w * 16) * 64);
            load_lds16(vb + (size_t)sr1 * SEQ + sc1 * 8, Vs + (w * 16 + 8) * 64);
        }
        __syncthreads();   // vmcnt drained -> LDS ready

        const bool diag = (kt >= 2 * qt);
        const float cb = slope2 * (float)(kt * 64);
        const int dt = kt * 64;

        // S blocks nt-outer: low register pressure
        #pragma unroll
        for (int nt = 0; nt < 4; ++nt) {
            const float cn = cb + slope2 * (float)(nt * 16);
            f32x4 sc[2];
            #pragma unroll
            for (int m = 0; m < 2; ++m)
                #pragma unroll
                for (int r = 0; r < 4; ++r) sc[m][r] = pre[m][r] + cn;
            #pragma unroll
            for (int ks = 0; ks < 2; ++ks) {
                bf16x8 kf = *(const bf16x8*)(Ks + (nt * 16 + lmod) * 64 + ((ks ? cx1 : cx0) << 3));
                #pragma unroll
                for (int m = 0; m < 2; ++m)
                    sc[m] = __builtin_amdgcn_mfma_f32_16x16x32_bf16(qf[m][ks], kf, sc[m], 0, 0, 0);
            }
            if (diag) {
                #pragma unroll
                for (int m = 0; m < 2; ++m)
                    #pragma unroll
                    for (int r = 0; r < 4; ++r) {
                        float v = sc[m][r];
                        if (dt + nt * 16 - r + db[m] > 0) v = -1e30f;
                        const float p = __builtin_amdgcn_exp2f(v);
                        lsum[m][r] += p;
                        pw[(m * 16 + ldiv * 4 + r) * PPAD + nt * 16 + lmod] = f2bf_trunc(p);
                    }
            } else {
                #pragma unroll
                for (int m = 0; m < 2; ++m)
                    #pragma unroll
                    for (int r = 0; r < 4; ++r) {
                        const float p = __builtin_amdgcn_exp2f(sc[m][r]);
                        lsum[m][r] += p;
                        pw[(m * 16 + ldiv * 4 + r) * PPAD + nt * 16 + lmod] = f2bf_trunc(p);
                    }
            }
        }

        // P: same-wave LDS RAW (lgkmcnt ordering, no barrier)
        bf16x8 pa[2][2];
        #pragma unroll
        for (int m = 0; m < 2; ++m) {
            pa[m][0] = *(const bf16x8*)(pw + (m * 16 + lmod) * PPAD + ldiv * 8);
            pa[m][1] = *(const bf16x8*)(pw + (m * 16 + lmod) * PPAD + 32 + ldiv * 8);
        }
        #pragma unroll
        for (int ks = 0; ks < 2; ++ks) {
            const int cxo = (ks ? cx1 : cx0) << 3;
            #pragma unroll
            for (int nt = 0; nt < 4; ++nt) {
                bf16x8 vf = *(const bf16x8*)(Vs + (nt * 16 + lmod) * 64 + cxo);
                #pragma unroll
                for (int m = 0; m < 2; ++m)
                    O[m][nt] = __builtin_amdgcn_mfma_f32_16x16x32_bf16(pa[m][ks], vf, O[m][nt], 0, 0, 0);
            }
        }
    }

    // reduce row sums across 16-lane groups
    #pragma unroll
    for (int m = 0; m < 2; ++m)
        #pragma unroll
        for (int r = 0; r < 4; ++r) {
            float v = lsum[m][r];
            v += __shfl_xor(v, 1, 16);
            v += __shfl_xor(v, 2, 16);
            v += __shfl_xor(v, 4, 16);
            v += __shfl_xor(v, 8, 16);
            lsum[m][r] = v;
        }

    float* ob = s ? o1 : o0;
    float* lb = s ? ls1 : ls0;
    #pragma unroll
    for (int m = 0; m < 2; ++m) {
        const int i0 = rowbase + m * 16 + ldiv * 4;
        #pragma unroll
        for (int nt = 0; nt < 4; ++nt)
            #pragma unroll
            for (int r = 0; r < 4; ++r)
                ob[(size_t)(i0 + r) * DM + h * 64 + nt * 16 + lmod] = O[m][nt][r];
    }
    if (lmod == 0) {
        #pragma unroll
        for (int m = 0; m < 2; ++m)
            #pragma unroll
            for (int r = 0; r < 4; ++r)
                lb[h * SEQ + rowbase + m * 16 + ldiv * 4 + r] = lsum[m][r];
    }
}

// ---- combine: out = (O0 + O1) / (l0 + l1) ----
__global__ __launch_bounds__(256) void combine(float* __restrict__ out,
                                               const float* __restrict__ opart,
                                               const float* __restrict__ ls0,
                                               const float* __restrict__ ls1) {
    const int i8 = (blockIdx.x * 256 + threadIdx.x) * 8;
    const int row = i8 >> 10, col = i8 & 1023, h = col >> 6;
    const float l = ls0[h * SEQ + row] + ls1[h * SEQ + row];
    const float rc = 1.0f / l;
    float4 a0 = *(const float4*)(out + i8);
    float4 a1 = *(const float4*)(out + i8 + 4);
    float4 b0 = *(const float4*)(opart + i8);
    float4 b1 = *(const float4*)(opart + i8 + 4);
    float4 c0, c1;
    c0.x = (a0.x + b0.x) * rc; c0.y = (a0.y + b0.y) * rc;
    c0.z = (a0.z + b0.z) * rc; c0.w = (a0.w + b0.w) * rc;
    c1.x = (a1.x + b1.x) * rc; c1.y = (a1.y + b1.y) * rc;
    c1.z = (a1.z + b1.z) * rc; c1.w = (a1.w + b1.w) * rc;
    *(float4*)(out + i8) = c0;
    *(float4*)(out + i8 + 4) = c1;
}

extern "C" void kernel_launch(void* const* d_in, const int* in_sizes, int n_in,
                              void* d_out, int out_size, void* d_ws, size_t ws_size,
                              hipStream_t stream) {
    const float* x = (const float*)d_in[0];   // [1,4096,1024] fp32
    const float* w = (const float*)d_in[1];   // [1024,3072] fp32
    float* out = (float*)d_out;

    char* ws = (char*)d_ws;
    short* kq    = (short*)(ws);                        // 16 MB: K|Q [4096][2048]
    short* vt    = (short*)(ws + ((size_t)16 << 20));   //  8 MB: V^T [16][64][4096]
    short* xb    = (short*)(ws + ((size_t)24 << 20));   //  8 MB: x bf16 (dead after gemm)
    short* wtb   = (short*)(ws + ((size_t)32 << 20));   //  6 MB: w^T bf16 (dead after gemm)
    float* opart = (float*)(ws + ((size_t)24 << 20));   // 16 MB: split-1 partial O (reuses xb/wtb)
    float* ls0   = (float*)(ws + ((size_t)40 << 20));   // 256 KB
    float* ls1   = (float*)(ws + ((size_t)40 << 20) + (256 << 10));

    cvt_fused<<<2048 + 768, 256, 0, stream>>>(x, w, xb, wtb);
    qkv_gemm <<<dim3(SEQ / 128, 3072 / 128), 256, 0, stream>>>(xb, wtb, kq, vt);
    attn     <<<1024, 256, 0, stream>>>(kq, vt, out, opart, ls0, ls1);
    combine  <<<SEQ * DM / (256 * 8), 256, 0, stream>>>(out, opart, ls0, ls1);
}